// Round 2
// baseline (1441.472 us; speedup 1.0000x reference)
//
#include <hip/hip_runtime.h>

#define NN 50000
#define NE 800000
#define INC 32
#define HH 64
#define H2 128
#define OC 16
#define ON 17
#define NL 4
#define MEPS 1e-7f
#define LNE 1e-5f
#define SCAN_BLOCKS 196   /* ceil(50000/256) */

// ---------- ordered-uint encoding for float atomic max ----------
__device__ __forceinline__ unsigned fenc(float x) {
    unsigned u = __float_as_uint(x);
    return (u & 0x80000000u) ? ~u : (u | 0x80000000u);
}
__device__ __forceinline__ float fdec(unsigned u) {
    return (u & 0x80000000u) ? __uint_as_float(u & 0x7fffffffu)
                             : __uint_as_float(~u);
}
// ---------- bf16 helpers (RNE) ----------
__device__ __forceinline__ unsigned short f2b(float x) {
    unsigned b = __float_as_uint(x);
    b += 0x7FFFu + ((b >> 16) & 1u);
    return (unsigned short)(b >> 16);
}
__device__ __forceinline__ float b2f(unsigned short u) {
    return __uint_as_float(((unsigned)u) << 16);
}

// ---------- CSR build ----------
__global__ __launch_bounds__(256) void k_hist2(const int* __restrict__ dst, int* __restrict__ counts,
                                               int* __restrict__ rank) {
    int e = blockIdx.x * 256 + threadIdx.x;
    if (e < NE) rank[e] = atomicAdd(&counts[dst[e]], 1);
}

__global__ __launch_bounds__(256) void k_scan1(const int* __restrict__ counts,
                                               int* __restrict__ incl, int* __restrict__ bsums) {
    __shared__ int s[256];
    int t = threadIdx.x;
    int i = blockIdx.x * 256 + t;
    int v = (i < NN) ? counts[i] : 0;
    s[t] = v;
    __syncthreads();
    for (int off = 1; off < 256; off <<= 1) {
        int x = (t >= off) ? s[t - off] : 0;
        __syncthreads();
        s[t] += x;
        __syncthreads();
    }
    if (i < NN) incl[i] = s[t];
    if (t == 255) bsums[blockIdx.x] = s[255];
}

__global__ __launch_bounds__(256) void k_scan2(int* __restrict__ bsums) {
    __shared__ int s[256];
    int t = threadIdx.x;
    int v = (t < SCAN_BLOCKS) ? bsums[t] : 0;
    s[t] = v;
    __syncthreads();
    for (int off = 1; off < 256; off <<= 1) {
        int x = (t >= off) ? s[t - off] : 0;
        __syncthreads();
        s[t] += x;
        __syncthreads();
    }
    if (t < SCAN_BLOCKS) bsums[t] = s[t] - v;  // exclusive
}

__global__ __launch_bounds__(256) void k_scan3(const int* __restrict__ counts,
                                               int* __restrict__ rowst, const int* __restrict__ bsums) {
    int i = blockIdx.x * 256 + threadIdx.x;
    if (i < NN) rowst[i] = rowst[i] - counts[i] + bsums[blockIdx.x];
}

__global__ __launch_bounds__(256) void k_scatter2(const int* __restrict__ src, const int* __restrict__ dst,
                                                  const int* __restrict__ rank, const int* __restrict__ rowst,
                                                  int* __restrict__ ssrc) {
    int e = blockIdx.x * 256 + threadIdx.x;
    if (e < NE) ssrc[rowst[dst[e]] + rank[e]] = src[e];
}

// ---------- node encoder: h = x @ W + b  ([N,32]@[32,64]), also bf16 shadow ----------
__global__ __launch_bounds__(256) void k_encoder(const float* __restrict__ x, const float* __restrict__ W,
                                                 const float* __restrict__ b, float* __restrict__ h,
                                                 unsigned short* __restrict__ hbf) {
    __shared__ float Ws[INC * HH];
    __shared__ float bs[HH];
    int tid = threadIdx.x;
    for (int i = tid; i < INC * HH; i += 256) Ws[i] = W[i];
    if (tid < HH) bs[tid] = b[tid];
    __syncthreads();
    int wid = tid >> 6, lane = tid & 63;
    int n = blockIdx.x * 4 + wid;
    if (n >= NN) return;
    float v = (lane < INC) ? x[(size_t)n * INC + lane] : 0.f;
    float acc = bs[lane];
    #pragma unroll
    for (int k = 0; k < INC; ++k)
        acc += __shfl(v, k) * Ws[k * HH + lane];
    h[(size_t)n * HH + lane] = acc;
    hbf[(size_t)n * HH + lane] = f2b(acc);
}

// ---------- per-dst softmax aggregation, dual-row gathers ----------
__global__ __launch_bounds__(256) void k_agg(const float* __restrict__ y,
                                             const unsigned short* __restrict__ ybf,
                                             const int* __restrict__ rowst,
                                             const int* __restrict__ counts, const int* __restrict__ ssrc,
                                             const float* __restrict__ tp, float* __restrict__ ag) {
    int tid = threadIdx.x;
    int wid = tid >> 6, lane = tid & 63;
    int n = blockIdx.x * 4 + wid;
    if (n >= NN) return;
    float tval = *tp;
    int start = rowst[n];
    int deg = counts[n];
    float Sa = 0.f, Sma = 0.f;
    if (deg > 0 && deg <= 64) {
        int myidx = (lane < deg) ? ssrc[start + lane] : 0;
        int half = lane >> 5;      // edge parity this lane handles
        int col = lane & 31;       // channel-pair index
        float Sa0 = 0.f, Sa1 = 0.f, Sm0 = 0.f, Sm1 = 0.f;
        for (int base = 0; base < deg; base += 16) {
            float c0[8], c1[8];
            int eidx[8];
            #pragma unroll
            for (int i = 0; i < 8; ++i) {
                int e = base + 2 * i + half;
                eidx[i] = e;
                int es = (e < deg) ? e : (deg - 1);
                int s = __shfl(myidx, es);
                unsigned v = *(const unsigned*)(ybf + (size_t)s * HH + col * 2);
                c0[i] = b2f((unsigned short)(v & 0xffffu));
                c1[i] = b2f((unsigned short)(v >> 16));
            }
            #pragma unroll
            for (int i = 0; i < 8; ++i) {
                bool ok = eidx[i] < deg;
                float m0 = fmaxf(c0[i], 0.f) + MEPS;
                float m1 = fmaxf(c1[i], 0.f) + MEPS;
                float a0 = ok ? __expf(tval * m0) : 0.f;
                float a1 = ok ? __expf(tval * m1) : 0.f;
                Sa0 += a0; Sm0 += m0 * a0;
                Sa1 += a1; Sm1 += m1 * a1;
            }
        }
        Sa0 += __shfl_xor(Sa0, 32); Sa1 += __shfl_xor(Sa1, 32);
        Sm0 += __shfl_xor(Sm0, 32); Sm1 += __shfl_xor(Sm1, 32);
        int srcl = lane >> 1;
        float saA = __shfl(Sa0, srcl), saB = __shfl(Sa1, srcl);
        float smA = __shfl(Sm0, srcl), smB = __shfl(Sm1, srcl);
        Sa = (lane & 1) ? saB : saA;
        Sma = (lane & 1) ? smB : smA;
    } else if (deg > 64) {
        for (int e = 0; e < deg; ++e) {
            int s = ssrc[start + e];
            float v = b2f(ybf[(size_t)s * HH + lane]);
            float m = fmaxf(v, 0.f) + MEPS;
            float a = __expf(tval * m);
            Sa += a; Sma += m * a;
        }
    }
    float agg = Sma / fmaxf(Sa, MEPS);  // deg==0 -> 0
    ag[(size_t)n * HH + lane] = agg + y[(size_t)n * HH + lane];
}

// ---------- fused MLP: U = ag@W1+b1 ; U = relu(LN128(U)) ; o = U@W2+b2 (+hres) -> hout
//            optional epilogue: y = relu(LN64(o)) + bf16 shadow (next layer's input)
// GEMM inner loops read both A and W as b128 over 4 k's (LDS-issue bound kernel).
__global__ __launch_bounds__(256) void k_mlp(
    const float* __restrict__ ag,
    const float* __restrict__ W1, const float* __restrict__ b1,
    const float* __restrict__ mlg, const float* __restrict__ mlb,
    const float* __restrict__ W2, const float* __restrict__ b2,
    const float* __restrict__ hres, float* __restrict__ hout,
    const float* __restrict__ lng1, const float* __restrict__ lnb1,
    float* __restrict__ y, unsigned short* __restrict__ ybf)
{
    __shared__ float As[64 * 68];        // input tile (stride 68: 16B-aligned rows, 2-way max)
    __shared__ float Us[64 * 132];       // U tile (stride 132: 16B-aligned, bank-stagger 4)
    __shared__ float Wb[64 * 64];        // 16KB weight chunk
    __shared__ float ps[256], psq[256], mus[64], rss[64];
    __shared__ float bbA[H2], mg[H2], mbv[H2], bbB[HH], lgN[HH], lbN[HH];
    int tid = threadIdx.x;
    int nb = blockIdx.x * 64;
    int tx = tid & 15, ty = tid >> 4;
    int r0 = ty * 4, c0 = tx * 4;

    // ---- stage input tile, W1 half 0, and small vectors
    {
        int row = tid >> 2, cb = (tid & 3) * 16;
        int n = nb + row;
        float4* dp = (float4*)(As + row * 68 + cb);
        if (n < NN) {
            const float4* sp = (const float4*)(ag + (size_t)n * HH + cb);
            #pragma unroll
            for (int i = 0; i < 4; ++i) dp[i] = sp[i];
        } else {
            float4 z = {0.f, 0.f, 0.f, 0.f};
            #pragma unroll
            for (int i = 0; i < 4; ++i) dp[i] = z;
        }
    }
    for (int i = tid; i < 1024; i += 256) {
        int k = i >> 4, cq = i & 15;
        ((float4*)Wb)[i] = ((const float4*)W1)[k * 32 + cq];           // cols 0..63
    }
    if (tid < H2) { bbA[tid] = b1[tid]; mg[tid] = mlg[tid]; mbv[tid] = mlb[tid]; }
    else if (tid < H2 + HH) {
        int j = tid - H2;
        bbB[j] = b2[j];
        if (lng1) { lgN[j] = lng1[j]; lbN[j] = lnb1[j]; }
    }
    __syncthreads();

    // ---- gemmA pass 0 (output cols 0..63)
    {
        float acc[4][4] = {};
        #pragma unroll
        for (int k = 0; k < HH; k += 4) {
            float4 w0 = ((const float4*)Wb)[k * 16 + tx];
            float4 w1 = ((const float4*)Wb)[(k + 1) * 16 + tx];
            float4 w2 = ((const float4*)Wb)[(k + 2) * 16 + tx];
            float4 w3 = ((const float4*)Wb)[(k + 3) * 16 + tx];
            #pragma unroll
            for (int r = 0; r < 4; ++r) {
                float4 a = *(const float4*)(As + (r0 + r) * 68 + k);
                acc[r][0] += a.x * w0.x + a.y * w1.x + a.z * w2.x + a.w * w3.x;
                acc[r][1] += a.x * w0.y + a.y * w1.y + a.z * w2.y + a.w * w3.y;
                acc[r][2] += a.x * w0.z + a.y * w1.z + a.z * w2.z + a.w * w3.z;
                acc[r][3] += a.x * w0.w + a.y * w1.w + a.z * w2.w + a.w * w3.w;
            }
        }
        #pragma unroll
        for (int r = 0; r < 4; ++r) {
            float4 o;
            o.x = acc[r][0] + bbA[c0];     o.y = acc[r][1] + bbA[c0 + 1];
            o.z = acc[r][2] + bbA[c0 + 2]; o.w = acc[r][3] + bbA[c0 + 3];
            *(float4*)(Us + (r0 + r) * 132 + c0) = o;
        }
    }
    __syncthreads();
    for (int i = tid; i < 1024; i += 256) {
        int k = i >> 4, cq = i & 15;
        ((float4*)Wb)[i] = ((const float4*)W1)[k * 32 + 16 + cq];      // cols 64..127
    }
    __syncthreads();

    // ---- gemmA pass 1 (output cols 64..127)
    {
        float acc[4][4] = {};
        #pragma unroll
        for (int k = 0; k < HH; k += 4) {
            float4 w0 = ((const float4*)Wb)[k * 16 + tx];
            float4 w1 = ((const float4*)Wb)[(k + 1) * 16 + tx];
            float4 w2 = ((const float4*)Wb)[(k + 2) * 16 + tx];
            float4 w3 = ((const float4*)Wb)[(k + 3) * 16 + tx];
            #pragma unroll
            for (int r = 0; r < 4; ++r) {
                float4 a = *(const float4*)(As + (r0 + r) * 68 + k);
                acc[r][0] += a.x * w0.x + a.y * w1.x + a.z * w2.x + a.w * w3.x;
                acc[r][1] += a.x * w0.y + a.y * w1.y + a.z * w2.y + a.w * w3.y;
                acc[r][2] += a.x * w0.z + a.y * w1.z + a.z * w2.z + a.w * w3.z;
                acc[r][3] += a.x * w0.w + a.y * w1.w + a.z * w2.w + a.w * w3.w;
            }
        }
        #pragma unroll
        for (int r = 0; r < 4; ++r) {
            float4 o;
            o.x = acc[r][0] + bbA[64 + c0];     o.y = acc[r][1] + bbA[64 + c0 + 1];
            o.z = acc[r][2] + bbA[64 + c0 + 2]; o.w = acc[r][3] + bbA[64 + c0 + 3];
            *(float4*)(Us + (r0 + r) * 132 + 64 + c0) = o;
        }
    }
    __syncthreads();

    // ---- LN(128) partials; stage W2 rows 0..63 in the shadow of the reduction
    {
        int row = tid >> 2, q = tid & 3;
        const float* rp = Us + row * 132;
        float s = 0.f, sq = 0.f;
        #pragma unroll
        for (int i = 0; i < 32; ++i) { float v = rp[i * 4 + q]; s += v; sq += v * v; }
        ps[tid] = s; psq[tid] = sq;
    }
    for (int i = tid; i < 1024; i += 256)
        ((float4*)Wb)[i] = ((const float4*)W2)[i];                     // k-rows 0..63
    __syncthreads();
    if (tid < 64) {
        float s = ps[tid * 4] + ps[tid * 4 + 1] + ps[tid * 4 + 2] + ps[tid * 4 + 3];
        float sq = psq[tid * 4] + psq[tid * 4 + 1] + psq[tid * 4 + 2] + psq[tid * 4 + 3];
        float mu = s * (1.f / 128.f);
        float var = sq * (1.f / 128.f) - mu * mu;
        mus[tid] = mu;
        rss[tid] = rsqrtf(fmaxf(var, 0.f) + LNE);
    }
    __syncthreads();
    {
        int row = tid >> 2, q = tid & 3;
        float mu = mus[row], rs = rss[row];
        float* rp = Us + row * 132;
        #pragma unroll
        for (int i = 0; i < 32; ++i) {
            int c = i * 4 + q;
            rp[c] = fmaxf((rp[c] - mu) * rs * mg[c] + mbv[c], 0.f);
        }
    }
    __syncthreads();

    // ---- gemmB (k 0..63, then k 64..127)
    float acc2[4][4] = {};
    #pragma unroll
    for (int k = 0; k < 64; k += 4) {
        float4 w0 = ((const float4*)Wb)[k * 16 + tx];
        float4 w1 = ((const float4*)Wb)[(k + 1) * 16 + tx];
        float4 w2 = ((const float4*)Wb)[(k + 2) * 16 + tx];
        float4 w3 = ((const float4*)Wb)[(k + 3) * 16 + tx];
        #pragma unroll
        for (int r = 0; r < 4; ++r) {
            float4 a = *(const float4*)(Us + (r0 + r) * 132 + k);
            acc2[r][0] += a.x * w0.x + a.y * w1.x + a.z * w2.x + a.w * w3.x;
            acc2[r][1] += a.x * w0.y + a.y * w1.y + a.z * w2.y + a.w * w3.y;
            acc2[r][2] += a.x * w0.z + a.y * w1.z + a.z * w2.z + a.w * w3.z;
            acc2[r][3] += a.x * w0.w + a.y * w1.w + a.z * w2.w + a.w * w3.w;
        }
    }
    __syncthreads();
    for (int i = tid; i < 1024; i += 256)
        ((float4*)Wb)[i] = ((const float4*)W2)[1024 + i];              // k-rows 64..127
    __syncthreads();
    #pragma unroll
    for (int k = 0; k < 64; k += 4) {
        float4 w0 = ((const float4*)Wb)[k * 16 + tx];
        float4 w1 = ((const float4*)Wb)[(k + 1) * 16 + tx];
        float4 w2 = ((const float4*)Wb)[(k + 2) * 16 + tx];
        float4 w3 = ((const float4*)Wb)[(k + 3) * 16 + tx];
        #pragma unroll
        for (int r = 0; r < 4; ++r) {
            float4 a = *(const float4*)(Us + (r0 + r) * 132 + 64 + k);
            acc2[r][0] += a.x * w0.x + a.y * w1.x + a.z * w2.x + a.w * w3.x;
            acc2[r][1] += a.x * w0.y + a.y * w1.y + a.z * w2.y + a.w * w3.y;
            acc2[r][2] += a.x * w0.z + a.y * w1.z + a.z * w2.z + a.w * w3.z;
            acc2[r][3] += a.x * w0.w + a.y * w1.w + a.z * w2.w + a.w * w3.w;
        }
    }

    // ---- epilogue: bias + residual, write h
    float4 o[4];
    #pragma unroll
    for (int r = 0; r < 4; ++r) {
        int n = nb + r0 + r;
        o[r].x = acc2[r][0] + bbB[c0];     o[r].y = acc2[r][1] + bbB[c0 + 1];
        o[r].z = acc2[r][2] + bbB[c0 + 2]; o[r].w = acc2[r][3] + bbB[c0 + 3];
        if (n < NN) {
            if (hres) {
                float4 hr = *(const float4*)(hres + (size_t)n * HH + c0);
                o[r].x += hr.x; o[r].y += hr.y; o[r].z += hr.z; o[r].w += hr.w;
            }
            *(float4*)(hout + (size_t)n * HH + c0) = o[r];
        }
    }
    if (!lng1) return;   // last layer: outg does the final LN itself (uniform exit)

    // ---- next-layer LN(64)+ReLU: row stats via LDS, values stay in registers
    #pragma unroll
    for (int r = 0; r < 4; ++r)
        *(float4*)(As + (r0 + r) * 68 + c0) = o[r];
    __syncthreads();
    {
        int row = tid >> 2, q = tid & 3;
        const float* rp = As + row * 68;
        float s = 0.f, sq = 0.f;
        #pragma unroll
        for (int i = 0; i < 16; ++i) { float v = rp[q + 4 * i]; s += v; sq += v * v; }
        ps[tid] = s; psq[tid] = sq;
    }
    __syncthreads();
    if (tid < 64) {
        float s = ps[tid * 4] + ps[tid * 4 + 1] + ps[tid * 4 + 2] + ps[tid * 4 + 3];
        float sq = psq[tid * 4] + psq[tid * 4 + 1] + psq[tid * 4 + 2] + psq[tid * 4 + 3];
        float mu = s * (1.f / 64.f);
        float var = sq * (1.f / 64.f) - mu * mu;
        mus[tid] = mu;
        rss[tid] = rsqrtf(fmaxf(var, 0.f) + LNE);
    }
    __syncthreads();
    #pragma unroll
    for (int r = 0; r < 4; ++r) {
        int row = r0 + r;
        int n = nb + row;
        if (n >= NN) continue;
        float mu = mus[row], rs = rss[row];
        float4 v;
        v.x = fmaxf((o[r].x - mu) * rs * lgN[c0]     + lbN[c0],     0.f);
        v.y = fmaxf((o[r].y - mu) * rs * lgN[c0 + 1] + lbN[c0 + 1], 0.f);
        v.z = fmaxf((o[r].z - mu) * rs * lgN[c0 + 2] + lbN[c0 + 2], 0.f);
        v.w = fmaxf((o[r].w - mu) * rs * lgN[c0 + 3] + lbN[c0 + 3], 0.f);
        *(float4*)(y + (size_t)n * HH + c0) = v;
        ushort4 p;
        p.x = f2b(v.x); p.y = f2b(v.y); p.z = f2b(v.z); p.w = f2b(v.w);
        *(ushort4*)(ybf + (size_t)n * HH + c0) = p;
    }
}

// ---------- fused final LN + both heads (no fence; k_gdec decodes) ----------
// Weight tile transposed to [j][k] (pad 68) so the GEMM reads b128 over 4 k's:
// 7 b128 per 4k instead of 28 b32 -> ~2x fewer LDS issue cycles (kernel is LDS-bound).
__global__ __launch_bounds__(256) void k_outg(const float* __restrict__ h,
                                              const float* __restrict__ lng, const float* __restrict__ lnb,
                                              const float* __restrict__ gW, const float* __restrict__ gb,
                                              const float* __restrict__ nW, const float* __restrict__ nbp,
                                              float* __restrict__ dout, unsigned* __restrict__ genc) {
    __shared__ float As[64 * 68];     // h tile, then normalized in place
    __shared__ float WcT[33 * 68];    // [j][k]: j<17 n-head, j in [17,33) g-head
    __shared__ float Os[64 * 40];     // output tile
    __shared__ float bs[40];
    __shared__ float lg[HH], lb[HH];
    __shared__ float ps[256], psq[256];
    __shared__ float mus[64], rss[64];
    int tid = threadIdx.x;
    int nb = blockIdx.x * 64;
    for (int i = tid; i < HH * ON; i += 256) { int k = i / ON, j = i - k * ON; WcT[j * 68 + k] = nW[i]; }
    for (int i = tid; i < HH * OC; i += 256) { int k = i / OC, j = i - k * OC; WcT[(ON + j) * 68 + k] = gW[i]; }
    if (tid < ON) bs[tid] = nbp[tid];
    else if (tid < 33) bs[tid] = gb[tid - ON];
    if (tid < HH) { lg[tid] = lng[tid]; lb[tid] = lnb[tid]; }
    {
        int row = tid >> 2, cb = (tid & 3) * 16;
        int n = nb + row;
        float4* dp = (float4*)(As + row * 68 + cb);
        if (n < NN) {
            const float4* sp = (const float4*)(h + (size_t)n * HH + cb);
            #pragma unroll
            for (int i = 0; i < 4; ++i) dp[i] = sp[i];
        } else {
            float4 z = {0.f, 0.f, 0.f, 0.f};
            #pragma unroll
            for (int i = 0; i < 4; ++i) dp[i] = z;
        }
    }
    __syncthreads();
    {
        int row = tid >> 2, q = tid & 3;
        const float* rp = As + row * 68;
        float s = 0.f, sq = 0.f;
        #pragma unroll
        for (int i = 0; i < 16; ++i) { float v = rp[q + 4 * i]; s += v; sq += v * v; }
        ps[tid] = s; psq[tid] = sq;
    }
    __syncthreads();
    if (tid < 64) {
        float s = ps[tid * 4] + ps[tid * 4 + 1] + ps[tid * 4 + 2] + ps[tid * 4 + 3];
        float sq = psq[tid * 4] + psq[tid * 4 + 1] + psq[tid * 4 + 2] + psq[tid * 4 + 3];
        float mu = s * (1.f / 64.f);
        float var = sq * (1.f / 64.f) - mu * mu;
        mus[tid] = mu;
        rss[tid] = rsqrtf(fmaxf(var, 0.f) + LNE);
    }
    __syncthreads();
    {
        int row = tid >> 2, q = tid & 3;
        float mu = mus[row], rs = rss[row];
        float* rp = As + row * 68;
        #pragma unroll
        for (int i = 0; i < 16; ++i) {
            int c = q + 4 * i;
            rp[c] = fmaxf((rp[c] - mu) * rs * lg[c] + lb[c], 0.f);
        }
    }
    __syncthreads();
    int tx = tid & 15, ty = tid >> 4;
    int r0 = ty * 4;
    float acc[4][3];
    #pragma unroll
    for (int r = 0; r < 4; ++r) {
        acc[r][0] = bs[tx]; acc[r][1] = bs[tx + 16]; acc[r][2] = bs[32];
    }
    #pragma unroll
    for (int k = 0; k < HH; k += 4) {
        float4 w0 = *(const float4*)(WcT + tx * 68 + k);
        float4 w1 = *(const float4*)(WcT + (16 + tx) * 68 + k);
        float4 w2 = *(const float4*)(WcT + 32 * 68 + k);
        #pragma unroll
        for (int r = 0; r < 4; ++r) {
            float4 a = *(const float4*)(As + (r0 + r) * 68 + k);
            acc[r][0] += a.x * w0.x + a.y * w0.y + a.z * w0.z + a.w * w0.w;
            acc[r][1] += a.x * w1.x + a.y * w1.y + a.z * w1.z + a.w * w1.w;
            acc[r][2] += a.x * w2.x + a.y * w2.y + a.z * w2.z + a.w * w2.w;
        }
    }
    #pragma unroll
    for (int r = 0; r < 4; ++r) {
        Os[(r0 + r) * 40 + tx] = acc[r][0];
        Os[(r0 + r) * 40 + 16 + tx] = acc[r][1];
        if (tx == 0) Os[(r0 + r) * 40 + 32] = acc[r][2];
    }
    __syncthreads();
    // n-head store: linear index is exactly row-major [n][17] -> coalesced
    for (int i = tid; i < 64 * ON; i += 256) {
        int r = i / ON, j = i - r * ON;
        int n = nb + r;
        if (n < NN) dout[OC + (size_t)n * ON + j] = Os[r * 40 + j];
    }
    // g-head block max
    if (tid < OC) {
        int rmax = NN - nb; if (rmax > 64) rmax = 64;
        float m = -INFINITY;
        for (int r = 0; r < rmax; ++r) m = fmaxf(m, Os[r * 40 + ON + tid]);
        atomicMax(&genc[tid], fenc(m));
    }
}

__global__ void k_gdec(const unsigned* __restrict__ genc, float* __restrict__ dout) {
    int t = threadIdx.x;
    if (t < OC) dout[t] = fdec(genc[t]);
}

// ---------- launch ----------
extern "C" void kernel_launch(void* const* d_in, const int* in_sizes, int n_in,
                              void* d_out, int out_size, void* d_ws, size_t ws_size,
                              hipStream_t stream) {
    const float* x     = (const float*)d_in[0];
    const float* nodeW = (const float*)d_in[1];
    const float* nodeB = (const float*)d_in[2];
    const float* W1    = (const float*)d_in[3];
    const float* b1    = (const float*)d_in[4];
    const float* mlg   = (const float*)d_in[5];
    const float* mlb   = (const float*)d_in[6];
    const float* W2    = (const float*)d_in[7];
    const float* b2    = (const float*)d_in[8];
    const float* tt    = (const float*)d_in[9];
    const float* lng   = (const float*)d_in[10];
    const float* lnb   = (const float*)d_in[11];
    const int*   ei    = (const int*)d_in[12];
    const float* gW    = (const float*)d_in[13];
    const float* gb    = (const float*)d_in[14];
    const float* nW    = (const float*)d_in[15];
    const float* nbp   = (const float*)d_in[16];
    float* out = (float*)d_out;

    char* ws = (char*)d_ws;
    size_t off = 0;
    auto alloc = [&](size_t bytes) -> void* {
        void* p = ws + off;
        off = (off + bytes + 255) & ~(size_t)255;
        return p;
    };
    int* counts    = (int*)alloc((size_t)NN * 4);
    unsigned* genc = (unsigned*)alloc(64);
    size_t zero_end = off;
    int* bsums = (int*)alloc(1024);
    int* rowst = (int*)alloc((size_t)NN * 4);
    int* ssrc  = (int*)alloc((size_t)NE * 4);
    float* h   = (float*)alloc((size_t)NN * HH * 4);
    float* y   = (float*)alloc((size_t)NN * HH * 4);
    float* ag  = (float*)alloc((size_t)NN * HH * 4);
    unsigned short* ybf = (unsigned short*)alloc((size_t)NN * HH * 2);
    int* rank = (int*)ag;   // alias: rank only lives during CSR build, ag only during layers

    const int* esrc = ei;
    const int* edst = ei + NE;

    hipMemsetAsync(d_ws, 0, zero_end, stream);

    k_hist2<<<(NE + 255) / 256, 256, 0, stream>>>(edst, counts, rank);
    k_scan1<<<SCAN_BLOCKS, 256, 0, stream>>>(counts, rowst, bsums);
    k_scan2<<<1, 256, 0, stream>>>(bsums);
    k_scan3<<<SCAN_BLOCKS, 256, 0, stream>>>(counts, rowst, bsums);
    k_scatter2<<<(NE + 255) / 256, 256, 0, stream>>>(esrc, edst, rank, rowst, ssrc);
    k_encoder<<<(NN + 3) / 4, 256, 0, stream>>>(x, nodeW, nodeB, h, ybf);

    for (int l = 0; l < NL; ++l) {
        const float* yin = (l == 0) ? h : y;
        k_agg<<<(NN + 3) / 4, 256, 0, stream>>>(yin, ybf, rowst, counts, ssrc, tt + l, ag);
        const float* ln1g = (l < NL - 1) ? (lng + (size_t)(l + 1) * HH) : nullptr;
        const float* ln1b = (l < NL - 1) ? (lnb + (size_t)(l + 1) * HH) : nullptr;
        k_mlp<<<(NN + 63) / 64, 256, 0, stream>>>(ag,
                                                  W1 + (size_t)l * HH * H2, b1 + (size_t)l * H2,
                                                  mlg + (size_t)l * H2, mlb + (size_t)l * H2,
                                                  W2 + (size_t)l * H2 * HH, b2 + (size_t)l * HH,
                                                  (l == 0) ? (const float*)nullptr : h, h,
                                                  ln1g, ln1b, y, ybf);
    }
    k_outg<<<(NN + 63) / 64, 256, 0, stream>>>(h, lng, lnb, gW, gb, nW, nbp, out, genc);
    k_gdec<<<1, 64, 0, stream>>>(genc, out);
}

// Round 3
// 539.728 us; speedup vs baseline: 2.6707x; 2.6707x over previous
//
#include <hip/hip_runtime.h>

#define NN 50000
#define NE 800000
#define INC 32
#define HH 64
#define H2 128
#define OC 16
#define ON 17
#define NL 4
#define MEPS 1e-7f
#define LNE 1e-5f
#define SCAN_BLOCKS 196   /* ceil(50000/256) */

// ---------- ordered-uint encoding for float atomic max ----------
__device__ __forceinline__ unsigned fenc(float x) {
    unsigned u = __float_as_uint(x);
    return (u & 0x80000000u) ? ~u : (u | 0x80000000u);
}
__device__ __forceinline__ float fdec(unsigned u) {
    return (u & 0x80000000u) ? __uint_as_float(u & 0x7fffffffu)
                             : __uint_as_float(~u);
}
// ---------- bf16 helpers (RNE) ----------
__device__ __forceinline__ unsigned short f2b(float x) {
    unsigned b = __float_as_uint(x);
    b += 0x7FFFu + ((b >> 16) & 1u);
    return (unsigned short)(b >> 16);
}
__device__ __forceinline__ float b2f(unsigned short u) {
    return __uint_as_float(((unsigned)u) << 16);
}

// ---------- CSR build ----------
__global__ __launch_bounds__(256) void k_hist2(const int* __restrict__ dst, int* __restrict__ counts,
                                               int* __restrict__ rank) {
    int e = blockIdx.x * 256 + threadIdx.x;
    if (e < NE) rank[e] = atomicAdd(&counts[dst[e]], 1);
}

__global__ __launch_bounds__(256) void k_scan1(const int* __restrict__ counts,
                                               int* __restrict__ incl, int* __restrict__ bsums) {
    __shared__ int s[256];
    int t = threadIdx.x;
    int i = blockIdx.x * 256 + t;
    int v = (i < NN) ? counts[i] : 0;
    s[t] = v;
    __syncthreads();
    for (int off = 1; off < 256; off <<= 1) {
        int x = (t >= off) ? s[t - off] : 0;
        __syncthreads();
        s[t] += x;
        __syncthreads();
    }
    if (i < NN) incl[i] = s[t];
    if (t == 255) bsums[blockIdx.x] = s[255];
}

__global__ __launch_bounds__(256) void k_scan2(int* __restrict__ bsums) {
    __shared__ int s[256];
    int t = threadIdx.x;
    int v = (t < SCAN_BLOCKS) ? bsums[t] : 0;
    s[t] = v;
    __syncthreads();
    for (int off = 1; off < 256; off <<= 1) {
        int x = (t >= off) ? s[t - off] : 0;
        __syncthreads();
        s[t] += x;
        __syncthreads();
    }
    if (t < SCAN_BLOCKS) bsums[t] = s[t] - v;  // exclusive
}

__global__ __launch_bounds__(256) void k_scan3(const int* __restrict__ counts,
                                               int* __restrict__ rowst, const int* __restrict__ bsums) {
    int i = blockIdx.x * 256 + threadIdx.x;
    if (i < NN) rowst[i] = rowst[i] - counts[i] + bsums[blockIdx.x];
}

__global__ __launch_bounds__(256) void k_scatter2(const int* __restrict__ src, const int* __restrict__ dst,
                                                  const int* __restrict__ rank, const int* __restrict__ rowst,
                                                  int* __restrict__ ssrc) {
    int e = blockIdx.x * 256 + threadIdx.x;
    if (e < NE) ssrc[rowst[dst[e]] + rank[e]] = src[e];
}

// ---------- node encoder: h = x @ W + b  ([N,32]@[32,64]), also bf16 shadow ----------
__global__ __launch_bounds__(256) void k_encoder(const float* __restrict__ x, const float* __restrict__ W,
                                                 const float* __restrict__ b, float* __restrict__ h,
                                                 unsigned short* __restrict__ hbf) {
    __shared__ float Ws[INC * HH];
    __shared__ float bs[HH];
    int tid = threadIdx.x;
    for (int i = tid; i < INC * HH; i += 256) Ws[i] = W[i];
    if (tid < HH) bs[tid] = b[tid];
    __syncthreads();
    int wid = tid >> 6, lane = tid & 63;
    int n = blockIdx.x * 4 + wid;
    if (n >= NN) return;
    float v = (lane < INC) ? x[(size_t)n * INC + lane] : 0.f;
    float acc = bs[lane];
    #pragma unroll
    for (int k = 0; k < INC; ++k)
        acc += __shfl(v, k) * Ws[k * HH + lane];
    h[(size_t)n * HH + lane] = acc;
    hbf[(size_t)n * HH + lane] = f2b(acc);
}

// ---------- per-dst softmax aggregation, dual-row gathers ----------
__global__ __launch_bounds__(256) void k_agg(const float* __restrict__ y,
                                             const unsigned short* __restrict__ ybf,
                                             const int* __restrict__ rowst,
                                             const int* __restrict__ counts, const int* __restrict__ ssrc,
                                             const float* __restrict__ tp, float* __restrict__ ag) {
    int tid = threadIdx.x;
    int wid = tid >> 6, lane = tid & 63;
    int n = blockIdx.x * 4 + wid;
    if (n >= NN) return;
    float tval = *tp;
    int start = rowst[n];
    int deg = counts[n];
    float Sa = 0.f, Sma = 0.f;
    if (deg > 0 && deg <= 64) {
        int myidx = (lane < deg) ? ssrc[start + lane] : 0;
        int half = lane >> 5;      // edge parity this lane handles
        int col = lane & 31;       // channel-pair index
        float Sa0 = 0.f, Sa1 = 0.f, Sm0 = 0.f, Sm1 = 0.f;
        for (int base = 0; base < deg; base += 16) {
            float c0[8], c1[8];
            int eidx[8];
            #pragma unroll
            for (int i = 0; i < 8; ++i) {
                int e = base + 2 * i + half;
                eidx[i] = e;
                int es = (e < deg) ? e : (deg - 1);
                int s = __shfl(myidx, es);
                unsigned v = *(const unsigned*)(ybf + (size_t)s * HH + col * 2);
                c0[i] = b2f((unsigned short)(v & 0xffffu));
                c1[i] = b2f((unsigned short)(v >> 16));
            }
            #pragma unroll
            for (int i = 0; i < 8; ++i) {
                bool ok = eidx[i] < deg;
                float m0 = fmaxf(c0[i], 0.f) + MEPS;
                float m1 = fmaxf(c1[i], 0.f) + MEPS;
                float a0 = ok ? __expf(tval * m0) : 0.f;
                float a1 = ok ? __expf(tval * m1) : 0.f;
                Sa0 += a0; Sm0 += m0 * a0;
                Sa1 += a1; Sm1 += m1 * a1;
            }
        }
        Sa0 += __shfl_xor(Sa0, 32); Sa1 += __shfl_xor(Sa1, 32);
        Sm0 += __shfl_xor(Sm0, 32); Sm1 += __shfl_xor(Sm1, 32);
        int srcl = lane >> 1;
        float saA = __shfl(Sa0, srcl), saB = __shfl(Sa1, srcl);
        float smA = __shfl(Sm0, srcl), smB = __shfl(Sm1, srcl);
        Sa = (lane & 1) ? saB : saA;
        Sma = (lane & 1) ? smB : smA;
    } else if (deg > 64) {
        for (int e = 0; e < deg; ++e) {
            int s = ssrc[start + e];
            float v = b2f(ybf[(size_t)s * HH + lane]);
            float m = fmaxf(v, 0.f) + MEPS;
            float a = __expf(tval * m);
            Sa += a; Sma += m * a;
        }
    }
    float agg = Sma / fmaxf(Sa, MEPS);  // deg==0 -> 0
    ag[(size_t)n * HH + lane] = agg + y[(size_t)n * HH + lane];
}

// ---------- fused MLP: U = ag@W1+b1 ; U = relu(LN128(U)) ; o = U@W2+b2 (+hres) -> hout
//            optional epilogue: y = relu(LN64(o)) + bf16 shadow (next layer's input)
// NOTE: inner loops MUST stay k+=2/float2-A form. The k+=4/float4 variant spills
// (VGPR=256, 380MB scratch write/dispatch, 287us vs ~60us). Measured round 2.
__global__ __launch_bounds__(256) void k_mlp(
    const float* __restrict__ ag,
    const float* __restrict__ W1, const float* __restrict__ b1,
    const float* __restrict__ mlg, const float* __restrict__ mlb,
    const float* __restrict__ W2, const float* __restrict__ b2,
    const float* __restrict__ hres, float* __restrict__ hout,
    const float* __restrict__ lng1, const float* __restrict__ lnb1,
    float* __restrict__ y, unsigned short* __restrict__ ybf)
{
    __shared__ float As[64 * 68];        // input tile (stride 68: 16B-aligned rows)
    __shared__ float Us[64 * 132];       // U tile (stride 132: 16B-aligned)
    __shared__ float Wb[64 * 64];        // 16KB weight chunk
    __shared__ float ps[256], psq[256], mus[64], rss[64];
    __shared__ float bbA[H2], mg[H2], mbv[H2], bbB[HH], lgN[HH], lbN[HH];
    int tid = threadIdx.x;
    int nb = blockIdx.x * 64;
    int tx = tid & 15, ty = tid >> 4;
    int r0 = ty * 4, c0 = tx * 4;

    // ---- stage input tile, W1 half 0, and small vectors
    {
        int row = tid >> 2, cb = (tid & 3) * 16;
        int n = nb + row;
        float4* dp = (float4*)(As + row * 68 + cb);
        if (n < NN) {
            const float4* sp = (const float4*)(ag + (size_t)n * HH + cb);
            #pragma unroll
            for (int i = 0; i < 4; ++i) dp[i] = sp[i];
        } else {
            float4 z = {0.f, 0.f, 0.f, 0.f};
            #pragma unroll
            for (int i = 0; i < 4; ++i) dp[i] = z;
        }
    }
    for (int i = tid; i < 1024; i += 256) {
        int k = i >> 4, cq = i & 15;
        ((float4*)Wb)[i] = ((const float4*)W1)[k * 32 + cq];           // cols 0..63
    }
    if (tid < H2) { bbA[tid] = b1[tid]; mg[tid] = mlg[tid]; mbv[tid] = mlb[tid]; }
    else if (tid < H2 + HH) {
        int j = tid - H2;
        bbB[j] = b2[j];
        if (lng1) { lgN[j] = lng1[j]; lbN[j] = lnb1[j]; }
    }
    __syncthreads();

    // ---- gemmA pass 0 (output cols 0..63)
    {
        float acc[4][4] = {};
        #pragma unroll 8
        for (int k = 0; k < HH; k += 2) {
            float4 w0 = ((const float4*)Wb)[k * 16 + tx];
            float4 w1 = ((const float4*)Wb)[(k + 1) * 16 + tx];
            #pragma unroll
            for (int r = 0; r < 4; ++r) {
                float2 a2 = *(const float2*)(As + (r0 + r) * 68 + k);
                acc[r][0] += a2.x * w0.x + a2.y * w1.x;
                acc[r][1] += a2.x * w0.y + a2.y * w1.y;
                acc[r][2] += a2.x * w0.z + a2.y * w1.z;
                acc[r][3] += a2.x * w0.w + a2.y * w1.w;
            }
        }
        #pragma unroll
        for (int r = 0; r < 4; ++r) {
            float4 o;
            o.x = acc[r][0] + bbA[c0];     o.y = acc[r][1] + bbA[c0 + 1];
            o.z = acc[r][2] + bbA[c0 + 2]; o.w = acc[r][3] + bbA[c0 + 3];
            *(float4*)(Us + (r0 + r) * 132 + c0) = o;
        }
    }
    __syncthreads();
    for (int i = tid; i < 1024; i += 256) {
        int k = i >> 4, cq = i & 15;
        ((float4*)Wb)[i] = ((const float4*)W1)[k * 32 + 16 + cq];      // cols 64..127
    }
    __syncthreads();

    // ---- gemmA pass 1 (output cols 64..127)
    {
        float acc[4][4] = {};
        #pragma unroll 8
        for (int k = 0; k < HH; k += 2) {
            float4 w0 = ((const float4*)Wb)[k * 16 + tx];
            float4 w1 = ((const float4*)Wb)[(k + 1) * 16 + tx];
            #pragma unroll
            for (int r = 0; r < 4; ++r) {
                float2 a2 = *(const float2*)(As + (r0 + r) * 68 + k);
                acc[r][0] += a2.x * w0.x + a2.y * w1.x;
                acc[r][1] += a2.x * w0.y + a2.y * w1.y;
                acc[r][2] += a2.x * w0.z + a2.y * w1.z;
                acc[r][3] += a2.x * w0.w + a2.y * w1.w;
            }
        }
        #pragma unroll
        for (int r = 0; r < 4; ++r) {
            float4 o;
            o.x = acc[r][0] + bbA[64 + c0];     o.y = acc[r][1] + bbA[64 + c0 + 1];
            o.z = acc[r][2] + bbA[64 + c0 + 2]; o.w = acc[r][3] + bbA[64 + c0 + 3];
            *(float4*)(Us + (r0 + r) * 132 + 64 + c0) = o;
        }
    }
    __syncthreads();

    // ---- LN(128) partials; stage W2 rows 0..63 in the shadow of the reduction
    {
        int row = tid >> 2, q = tid & 3;
        const float* rp = Us + row * 132;
        float s = 0.f, sq = 0.f;
        #pragma unroll
        for (int i = 0; i < 32; ++i) { float v = rp[i * 4 + q]; s += v; sq += v * v; }
        ps[tid] = s; psq[tid] = sq;
    }
    for (int i = tid; i < 1024; i += 256)
        ((float4*)Wb)[i] = ((const float4*)W2)[i];                     // k-rows 0..63
    __syncthreads();
    if (tid < 64) {
        float s = ps[tid * 4] + ps[tid * 4 + 1] + ps[tid * 4 + 2] + ps[tid * 4 + 3];
        float sq = psq[tid * 4] + psq[tid * 4 + 1] + psq[tid * 4 + 2] + psq[tid * 4 + 3];
        float mu = s * (1.f / 128.f);
        float var = sq * (1.f / 128.f) - mu * mu;
        mus[tid] = mu;
        rss[tid] = rsqrtf(fmaxf(var, 0.f) + LNE);
    }
    __syncthreads();
    {
        int row = tid >> 2, q = tid & 3;
        float mu = mus[row], rs = rss[row];
        float* rp = Us + row * 132;
        #pragma unroll
        for (int i = 0; i < 32; ++i) {
            int c = i * 4 + q;
            rp[c] = fmaxf((rp[c] - mu) * rs * mg[c] + mbv[c], 0.f);
        }
    }
    __syncthreads();

    // ---- gemmB (k 0..63, then k 64..127)
    float acc2[4][4] = {};
    #pragma unroll 8
    for (int k = 0; k < 64; k += 2) {
        float4 w0 = ((const float4*)Wb)[k * 16 + tx];
        float4 w1 = ((const float4*)Wb)[(k + 1) * 16 + tx];
        #pragma unroll
        for (int r = 0; r < 4; ++r) {
            float2 a2 = *(const float2*)(Us + (r0 + r) * 132 + k);
            acc2[r][0] += a2.x * w0.x + a2.y * w1.x;
            acc2[r][1] += a2.x * w0.y + a2.y * w1.y;
            acc2[r][2] += a2.x * w0.z + a2.y * w1.z;
            acc2[r][3] += a2.x * w0.w + a2.y * w1.w;
        }
    }
    __syncthreads();
    for (int i = tid; i < 1024; i += 256)
        ((float4*)Wb)[i] = ((const float4*)W2)[1024 + i];              // k-rows 64..127
    __syncthreads();
    #pragma unroll 8
    for (int k = 0; k < 64; k += 2) {
        float4 w0 = ((const float4*)Wb)[k * 16 + tx];
        float4 w1 = ((const float4*)Wb)[(k + 1) * 16 + tx];
        #pragma unroll
        for (int r = 0; r < 4; ++r) {
            float2 a2 = *(const float2*)(Us + (r0 + r) * 132 + 64 + k);
            acc2[r][0] += a2.x * w0.x + a2.y * w1.x;
            acc2[r][1] += a2.x * w0.y + a2.y * w1.y;
            acc2[r][2] += a2.x * w0.z + a2.y * w1.z;
            acc2[r][3] += a2.x * w0.w + a2.y * w1.w;
        }
    }

    // ---- epilogue: bias + residual, write h
    float4 o[4];
    #pragma unroll
    for (int r = 0; r < 4; ++r) {
        int n = nb + r0 + r;
        o[r].x = acc2[r][0] + bbB[c0];     o[r].y = acc2[r][1] + bbB[c0 + 1];
        o[r].z = acc2[r][2] + bbB[c0 + 2]; o[r].w = acc2[r][3] + bbB[c0 + 3];
        if (n < NN) {
            if (hres) {
                float4 hr = *(const float4*)(hres + (size_t)n * HH + c0);
                o[r].x += hr.x; o[r].y += hr.y; o[r].z += hr.z; o[r].w += hr.w;
            }
            *(float4*)(hout + (size_t)n * HH + c0) = o[r];
        }
    }
    if (!lng1) return;   // last layer: outg does the final LN itself (uniform exit)

    // ---- next-layer LN(64)+ReLU: row stats via LDS, values stay in registers
    #pragma unroll
    for (int r = 0; r < 4; ++r)
        *(float4*)(As + (r0 + r) * 68 + c0) = o[r];
    __syncthreads();
    {
        int row = tid >> 2, q = tid & 3;
        const float* rp = As + row * 68;
        float s = 0.f, sq = 0.f;
        #pragma unroll
        for (int i = 0; i < 16; ++i) { float v = rp[q + 4 * i]; s += v; sq += v * v; }
        ps[tid] = s; psq[tid] = sq;
    }
    __syncthreads();
    if (tid < 64) {
        float s = ps[tid * 4] + ps[tid * 4 + 1] + ps[tid * 4 + 2] + ps[tid * 4 + 3];
        float sq = psq[tid * 4] + psq[tid * 4 + 1] + psq[tid * 4 + 2] + psq[tid * 4 + 3];
        float mu = s * (1.f / 64.f);
        float var = sq * (1.f / 64.f) - mu * mu;
        mus[tid] = mu;
        rss[tid] = rsqrtf(fmaxf(var, 0.f) + LNE);
    }
    __syncthreads();
    #pragma unroll
    for (int r = 0; r < 4; ++r) {
        int row = r0 + r;
        int n = nb + row;
        if (n >= NN) continue;
        float mu = mus[row], rs = rss[row];
        float4 v;
        v.x = fmaxf((o[r].x - mu) * rs * lgN[c0]     + lbN[c0],     0.f);
        v.y = fmaxf((o[r].y - mu) * rs * lgN[c0 + 1] + lbN[c0 + 1], 0.f);
        v.z = fmaxf((o[r].z - mu) * rs * lgN[c0 + 2] + lbN[c0 + 2], 0.f);
        v.w = fmaxf((o[r].w - mu) * rs * lgN[c0 + 3] + lbN[c0 + 3], 0.f);
        *(float4*)(y + (size_t)n * HH + c0) = v;
        ushort4 p;
        p.x = f2b(v.x); p.y = f2b(v.y); p.z = f2b(v.z); p.w = f2b(v.w);
        *(ushort4*)(ybf + (size_t)n * HH + c0) = p;
    }
}

// ---------- fused final LN + both heads (no fence; k_gdec decodes) ----------
// Weight tile transposed to [j][k] (pad 68): GEMM reads b128 over 4 k's.
__global__ __launch_bounds__(256) void k_outg(const float* __restrict__ h,
                                              const float* __restrict__ lng, const float* __restrict__ lnb,
                                              const float* __restrict__ gW, const float* __restrict__ gb,
                                              const float* __restrict__ nW, const float* __restrict__ nbp,
                                              float* __restrict__ dout, unsigned* __restrict__ genc) {
    __shared__ float As[64 * 68];     // h tile, then normalized in place
    __shared__ float WcT[33 * 68];    // [j][k]: j<17 n-head, j in [17,33) g-head
    __shared__ float Os[64 * 40];     // output tile
    __shared__ float bs[40];
    __shared__ float lg[HH], lb[HH];
    __shared__ float ps[256], psq[256];
    __shared__ float mus[64], rss[64];
    int tid = threadIdx.x;
    int nb = blockIdx.x * 64;
    for (int i = tid; i < HH * ON; i += 256) { int k = i / ON, j = i - k * ON; WcT[j * 68 + k] = nW[i]; }
    for (int i = tid; i < HH * OC; i += 256) { int k = i / OC, j = i - k * OC; WcT[(ON + j) * 68 + k] = gW[i]; }
    if (tid < ON) bs[tid] = nbp[tid];
    else if (tid < 33) bs[tid] = gb[tid - ON];
    if (tid < HH) { lg[tid] = lng[tid]; lb[tid] = lnb[tid]; }
    {
        int row = tid >> 2, cb = (tid & 3) * 16;
        int n = nb + row;
        float4* dp = (float4*)(As + row * 68 + cb);
        if (n < NN) {
            const float4* sp = (const float4*)(h + (size_t)n * HH + cb);
            #pragma unroll
            for (int i = 0; i < 4; ++i) dp[i] = sp[i];
        } else {
            float4 z = {0.f, 0.f, 0.f, 0.f};
            #pragma unroll
            for (int i = 0; i < 4; ++i) dp[i] = z;
        }
    }
    __syncthreads();
    {
        int row = tid >> 2, q = tid & 3;
        const float* rp = As + row * 68;
        float s = 0.f, sq = 0.f;
        #pragma unroll
        for (int i = 0; i < 16; ++i) { float v = rp[q + 4 * i]; s += v; sq += v * v; }
        ps[tid] = s; psq[tid] = sq;
    }
    __syncthreads();
    if (tid < 64) {
        float s = ps[tid * 4] + ps[tid * 4 + 1] + ps[tid * 4 + 2] + ps[tid * 4 + 3];
        float sq = psq[tid * 4] + psq[tid * 4 + 1] + psq[tid * 4 + 2] + psq[tid * 4 + 3];
        float mu = s * (1.f / 64.f);
        float var = sq * (1.f / 64.f) - mu * mu;
        mus[tid] = mu;
        rss[tid] = rsqrtf(fmaxf(var, 0.f) + LNE);
    }
    __syncthreads();
    {
        int row = tid >> 2, q = tid & 3;
        float mu = mus[row], rs = rss[row];
        float* rp = As + row * 68;
        #pragma unroll
        for (int i = 0; i < 16; ++i) {
            int c = q + 4 * i;
            rp[c] = fmaxf((rp[c] - mu) * rs * lg[c] + lb[c], 0.f);
        }
    }
    __syncthreads();
    int tx = tid & 15, ty = tid >> 4;
    int r0 = ty * 4;
    float acc[4][3];
    #pragma unroll
    for (int r = 0; r < 4; ++r) {
        acc[r][0] = bs[tx]; acc[r][1] = bs[tx + 16]; acc[r][2] = bs[32];
    }
    #pragma unroll
    for (int k = 0; k < HH; k += 4) {
        float4 w0 = *(const float4*)(WcT + tx * 68 + k);
        float4 w1 = *(const float4*)(WcT + (16 + tx) * 68 + k);
        float4 w2 = *(const float4*)(WcT + 32 * 68 + k);
        #pragma unroll
        for (int r = 0; r < 4; ++r) {
            float4 a = *(const float4*)(As + (r0 + r) * 68 + k);
            acc[r][0] += a.x * w0.x + a.y * w0.y + a.z * w0.z + a.w * w0.w;
            acc[r][1] += a.x * w1.x + a.y * w1.y + a.z * w1.z + a.w * w1.w;
            acc[r][2] += a.x * w2.x + a.y * w2.y + a.z * w2.z + a.w * w2.w;
        }
    }
    #pragma unroll
    for (int r = 0; r < 4; ++r) {
        Os[(r0 + r) * 40 + tx] = acc[r][0];
        Os[(r0 + r) * 40 + 16 + tx] = acc[r][1];
        if (tx == 0) Os[(r0 + r) * 40 + 32] = acc[r][2];
    }
    __syncthreads();
    // n-head store: linear index is exactly row-major [n][17] -> coalesced
    for (int i = tid; i < 64 * ON; i += 256) {
        int r = i / ON, j = i - r * ON;
        int n = nb + r;
        if (n < NN) dout[OC + (size_t)n * ON + j] = Os[r * 40 + j];
    }
    // g-head block max
    if (tid < OC) {
        int rmax = NN - nb; if (rmax > 64) rmax = 64;
        float m = -INFINITY;
        for (int r = 0; r < rmax; ++r) m = fmaxf(m, Os[r * 40 + ON + tid]);
        atomicMax(&genc[tid], fenc(m));
    }
}

__global__ void k_gdec(const unsigned* __restrict__ genc, float* __restrict__ dout) {
    int t = threadIdx.x;
    if (t < OC) dout[t] = fdec(genc[t]);
}

// ---------- launch ----------
extern "C" void kernel_launch(void* const* d_in, const int* in_sizes, int n_in,
                              void* d_out, int out_size, void* d_ws, size_t ws_size,
                              hipStream_t stream) {
    const float* x     = (const float*)d_in[0];
    const float* nodeW = (const float*)d_in[1];
    const float* nodeB = (const float*)d_in[2];
    const float* W1    = (const float*)d_in[3];
    const float* b1    = (const float*)d_in[4];
    const float* mlg   = (const float*)d_in[5];
    const float* mlb   = (const float*)d_in[6];
    const float* W2    = (const float*)d_in[7];
    const float* b2    = (const float*)d_in[8];
    const float* tt    = (const float*)d_in[9];
    const float* lng   = (const float*)d_in[10];
    const float* lnb   = (const float*)d_in[11];
    const int*   ei    = (const int*)d_in[12];
    const float* gW    = (const float*)d_in[13];
    const float* gb    = (const float*)d_in[14];
    const float* nW    = (const float*)d_in[15];
    const float* nbp   = (const float*)d_in[16];
    float* out = (float*)d_out;

    char* ws = (char*)d_ws;
    size_t off = 0;
    auto alloc = [&](size_t bytes) -> void* {
        void* p = ws + off;
        off = (off + bytes + 255) & ~(size_t)255;
        return p;
    };
    int* counts    = (int*)alloc((size_t)NN * 4);
    unsigned* genc = (unsigned*)alloc(64);
    size_t zero_end = off;
    int* bsums = (int*)alloc(1024);
    int* rowst = (int*)alloc((size_t)NN * 4);
    int* ssrc  = (int*)alloc((size_t)NE * 4);
    float* h   = (float*)alloc((size_t)NN * HH * 4);
    float* y   = (float*)alloc((size_t)NN * HH * 4);
    float* ag  = (float*)alloc((size_t)NN * HH * 4);
    unsigned short* ybf = (unsigned short*)alloc((size_t)NN * HH * 2);
    int* rank = (int*)ag;   // alias: rank only lives during CSR build, ag only during layers

    const int* esrc = ei;
    const int* edst = ei + NE;

    hipMemsetAsync(d_ws, 0, zero_end, stream);

    k_hist2<<<(NE + 255) / 256, 256, 0, stream>>>(edst, counts, rank);
    k_scan1<<<SCAN_BLOCKS, 256, 0, stream>>>(counts, rowst, bsums);
    k_scan2<<<1, 256, 0, stream>>>(bsums);
    k_scan3<<<SCAN_BLOCKS, 256, 0, stream>>>(counts, rowst, bsums);
    k_scatter2<<<(NE + 255) / 256, 256, 0, stream>>>(esrc, edst, rank, rowst, ssrc);
    k_encoder<<<(NN + 3) / 4, 256, 0, stream>>>(x, nodeW, nodeB, h, ybf);

    for (int l = 0; l < NL; ++l) {
        const float* yin = (l == 0) ? h : y;
        k_agg<<<(NN + 3) / 4, 256, 0, stream>>>(yin, ybf, rowst, counts, ssrc, tt + l, ag);
        const float* ln1g = (l < NL - 1) ? (lng + (size_t)(l + 1) * HH) : nullptr;
        const float* ln1b = (l < NL - 1) ? (lnb + (size_t)(l + 1) * HH) : nullptr;
        k_mlp<<<(NN + 63) / 64, 256, 0, stream>>>(ag,
                                                  W1 + (size_t)l * HH * H2, b1 + (size_t)l * H2,
                                                  mlg + (size_t)l * H2, mlb + (size_t)l * H2,
                                                  W2 + (size_t)l * H2 * HH, b2 + (size_t)l * HH,
                                                  (l == 0) ? (const float*)nullptr : h, h,
                                                  ln1g, ln1b, y, ybf);
    }
    k_outg<<<(NN + 63) / 64, 256, 0, stream>>>(h, lng, lnb, gW, gb, nW, nbp, out, genc);
    k_gdec<<<1, 64, 0, stream>>>(genc, out);
}